// Round 1
// baseline (1185.234 us; speedup 1.0000x reference)
//
#include <hip/hip_runtime.h>
#include <stdint.h>

#define B_N 4
#define C_N 512
#define SP_N 4096   // H*W
#define NG 32
#define CPG 16
#define EPS_ 1e-6f

using bf16x8 = __attribute__((ext_vector_type(8))) __bf16;
using f32x4  = __attribute__((ext_vector_type(4))) float;

#define MFMA16(a, b, c) __builtin_amdgcn_mfma_f32_16x16x32_bf16(a, b, c, 0, 0, 0)

__device__ __forceinline__ unsigned short f2bf(float f) {
    union { float f; unsigned u; } v; v.f = f;
    unsigned r = v.u + 0x7FFFu + ((v.u >> 16) & 1u);
    return (unsigned short)(r >> 16);
}

// ---------------- weight fp32 -> bf16 ----------------
__global__ void wconv(const float* __restrict__ a, const float* __restrict__ b,
                      const float* __restrict__ c, const float* __restrict__ d,
                      unsigned short* __restrict__ dst) {
    int m = blockIdx.y;
    const float* src = m == 0 ? a : m == 1 ? b : m == 2 ? c : d;
    int i = blockIdx.x * 256 + threadIdx.x;          // 0..65535 float4s
    float4 v = ((const float4*)src)[i];
    ushort4 o;
    o.x = f2bf(v.x); o.y = f2bf(v.y); o.z = f2bf(v.z); o.w = f2bf(v.w);
    ((ushort4*)(dst + (size_t)m * 262144))[i] = o;
}

// ---------------- GroupNorm -> h^T [B][N][C] bf16 ----------------
__global__ __launch_bounds__(512) void gn_kernel(const float* __restrict__ x,
        const float* __restrict__ gamma, const float* __restrict__ beta,
        unsigned short* __restrict__ h_t) {
    int blk = blockIdx.x;            // 0..127
    int b = blk >> 5, g = blk & 31;
    const float* xg = x + ((size_t)(b * C_N + g * CPG)) * SP_N;  // 16 contiguous channels
    int t = threadIdx.x;

    float s = 0.f, ss = 0.f;
    const float4* xv = (const float4*)xg;
    for (int i = t; i < (CPG * SP_N) / 4; i += 512) {
        float4 v = xv[i];
        s  += v.x + v.y + v.z + v.w;
        ss += v.x * v.x + v.y * v.y + v.z * v.z + v.w * v.w;
    }
    for (int m = 32; m; m >>= 1) { s += __shfl_xor(s, m); ss += __shfl_xor(ss, m); }
    __shared__ float rs[8], rss[8], stats[2];
    int wid = t >> 6;
    if ((t & 63) == 0) { rs[wid] = s; rss[wid] = ss; }
    __syncthreads();
    if (t == 0) {
        float a = 0.f, q = 0.f;
        for (int i = 0; i < 8; i++) { a += rs[i]; q += rss[i]; }
        float mean = a / (float)(CPG * SP_N);
        float var  = q / (float)(CPG * SP_N) - mean * mean;
        stats[0] = mean;
        stats[1] = rsqrtf(var + EPS_);
    }
    __shared__ float gam[CPG], bet[CPG];
    if (t < CPG) { gam[t] = gamma[g * CPG + t]; bet[t] = beta[g * CPG + t]; }
    __syncthreads();
    float mean = stats[0], rstd = stats[1];

    __shared__ unsigned short tile[CPG][130];
    unsigned short* hb = h_t + (size_t)b * SP_N * C_N;
    for (int n0 = 0; n0 < SP_N; n0 += 128) {
        __syncthreads();   // protect tile from previous write phase
#pragma unroll
        for (int p = 0; p < 4; p++) {
            int cc = p * 4 + (t >> 7);
            int nn = t & 127;
            float v = xg[(size_t)cc * SP_N + n0 + nn];
            v = (v - mean) * rstd * gam[cc] + bet[cc];
            tile[cc][nn] = f2bf(v);
        }
        __syncthreads();
#pragma unroll
        for (int p = 0; p < 4; p++) {
            int idx = p * 512 + t;
            int cc = idx & 15, nn = idx >> 4;
            hb[(size_t)(n0 + nn) * C_N + g * CPG + cc] = tile[cc][nn];
        }
    }
}

// ---------------- generic NT GEMM: out[m][n] = sum_k A[m][k]*B[n][k] + epilogue ----
// MODE 0: Q  (bias[n], *qs, bf16 out)   A=h_t[b], B=wq
// MODE 1: K  (bias[n], bf16 out)        A=h_t[b], B=wk
// MODE 2: V  (bias[m], bf16 out)        A=wv,     B=h_t[b]
// MODE 3: P  (bias[m]+resid, f32 out)   A=wp,     B=ao[b]
template<int MODE>
__global__ __launch_bounds__(256) void gemm_nt(
        const unsigned short* __restrict__ Ab,
        const unsigned short* __restrict__ Bb,
        void* __restrict__ outp,
        const float* __restrict__ bias,
        const float* __restrict__ resid,
        float qs) {
    __shared__ unsigned short at[128 * 64], bt[128 * 64];
    const int z = blockIdx.z;
    const size_t boff = (size_t)z * SP_N * C_N;
    const unsigned short* A;
    const unsigned short* Bm;
    int ldo;
    if (MODE <= 1) { A = Ab + boff; Bm = Bb; ldo = C_N; }
    else           { A = Ab;        Bm = Bb + boff; ldo = SP_N; }
    const int m0 = blockIdx.x * 128, n0 = blockIdx.y * 128;
    const int t = threadIdx.x;
    const int w = t >> 6, l = t & 63;
    const int wr = w >> 1, wc = w & 1;
    const int g = l >> 4, lr = l & 15;

    const f32x4 fz = {0.f, 0.f, 0.f, 0.f};
    f32x4 acc[4][4];
#pragma unroll
    for (int i = 0; i < 4; i++)
#pragma unroll
        for (int j = 0; j < 4; j++) acc[i][j] = fz;

    for (int k0 = 0; k0 < 512; k0 += 64) {
        __syncthreads();
#pragma unroll
        for (int r = 0; r < 4; r++) {
            int chunk = r * 256 + t;
            int row = chunk >> 3, ck = chunk & 7;
            uint4 da = *(const uint4*)(A + (size_t)(m0 + row) * 512 + k0 + ck * 8);
            *(uint4*)((char*)at + row * 128 + ((ck ^ (row & 7)) * 16)) = da;
            uint4 db = *(const uint4*)(Bm + (size_t)(n0 + row) * 512 + k0 + ck * 8);
            *(uint4*)((char*)bt + row * 128 + ((ck ^ (row & 7)) * 16)) = db;
        }
        __syncthreads();
#pragma unroll
        for (int ks = 0; ks < 2; ks++) {
            bf16x8 af[4], bfr[4];
#pragma unroll
            for (int mi = 0; mi < 4; mi++) {
                int row = wr * 64 + mi * 16 + lr;
                af[mi] = *(const bf16x8*)((const char*)at + row * 128 + (((ks * 4 + g) ^ (row & 7)) * 16));
            }
#pragma unroll
            for (int ni = 0; ni < 4; ni++) {
                int row = wc * 64 + ni * 16 + lr;
                bfr[ni] = *(const bf16x8*)((const char*)bt + row * 128 + (((ks * 4 + g) ^ (row & 7)) * 16));
            }
#pragma unroll
            for (int mi = 0; mi < 4; mi++)
#pragma unroll
                for (int ni = 0; ni < 4; ni++)
                    acc[mi][ni] = MFMA16(af[mi], bfr[ni], acc[mi][ni]);
        }
    }
#pragma unroll
    for (int mi = 0; mi < 4; mi++) {
#pragma unroll
        for (int ni = 0; ni < 4; ni++) {
            int col  = n0 + wc * 64 + ni * 16 + lr;
            int rowb = m0 + wr * 64 + mi * 16 + g * 4;
#pragma unroll
            for (int r = 0; r < 4; r++) {
                int row = rowb + r;
                float vv = acc[mi][ni][r];
                size_t oi = boff + (size_t)row * ldo + col;
                if (MODE == 0) {
                    vv = (vv + bias[col]) * qs;
                    ((unsigned short*)outp)[oi] = f2bf(vv);
                } else if (MODE == 1) {
                    vv += bias[col];
                    ((unsigned short*)outp)[oi] = f2bf(vv);
                } else if (MODE == 2) {
                    vv += bias[row];
                    ((unsigned short*)outp)[oi] = f2bf(vv);
                } else {
                    vv += bias[row] + resid[oi];
                    ((float*)outp)[oi] = vv;
                }
            }
        }
    }
}

// ---------------- flash attention ----------------
// q_t,k_t: [B][N][C] bf16 (q pre-scaled by c^-0.5 * log2e); v: [B][C][N] bf16
// ao: [B][N][C] bf16 (softmax(QK^T) V, normalized)
__global__ __launch_bounds__(256, 2) void attn_kernel(
        const unsigned short* __restrict__ qt,
        const unsigned short* __restrict__ kt,
        const unsigned short* __restrict__ vm,
        unsigned short* __restrict__ ao) {
    __shared__ unsigned short k_lds[32 * 512];     // [j][c], swizzled
    __shared__ unsigned short v_lds[512 * 40];     // [c][j], row stride 80B
    __shared__ unsigned short p_lds[4][16 * 64];   // per wave [i][j], swizzled

    const int b = blockIdx.y;
    const int t = threadIdx.x;
    const int w = t >> 6;
    const int l = t & 63;
    const int g = l >> 4;
    const int lr = l & 15;

    const unsigned short* qb = qt + ((size_t)b * SP_N + blockIdx.x * 64 + w * 16) * C_N;
    const unsigned short* kb = kt + (size_t)b * SP_N * C_N;
    const unsigned short* vb = vm + (size_t)b * C_N * SP_N;

    bf16x8 qf[16];
#pragma unroll
    for (int ks = 0; ks < 16; ks++)
        qf[ks] = *(const bf16x8*)(qb + (size_t)lr * C_N + ks * 32 + g * 8);

    const f32x4 fz = {0.f, 0.f, 0.f, 0.f};
    f32x4 oacc[32];
#pragma unroll
    for (int i = 0; i < 32; i++) oacc[i] = fz;
    f32x4 mst = {-1e30f, -1e30f, -1e30f, -1e30f};
    f32x4 lst = {0.f, 0.f, 0.f, 0.f};

    for (int j0 = 0; j0 < SP_N; j0 += 32) {
        __syncthreads();   // previous iteration's compute done before restage
#pragma unroll
        for (int r = 0; r < 8; r++) {              // stage K tile [32][512]
            int chunk = r * 256 + t;
            int row = chunk >> 6, ck = chunk & 63;
            uint4 d = *(const uint4*)(kb + (size_t)(j0 + row) * C_N + ck * 8);
            *(uint4*)((char*)k_lds + row * 1024 + ((ck ^ (row & 7)) * 16)) = d;
        }
#pragma unroll
        for (int r = 0; r < 8; r++) {              // stage V tile [512][32]
            int chunk = r * 256 + t;
            int c = chunk >> 2, jc = chunk & 3;
            uint4 d = *(const uint4*)(vb + (size_t)c * SP_N + j0 + jc * 8);
            *(uint4*)((char*)v_lds + c * 80 + jc * 16) = d;
        }
        __syncthreads();

        // S = Q K^T  (exp2 domain, scale folded into q)
        f32x4 s0 = fz, s1 = fz;
#pragma unroll
        for (int ks = 0; ks < 16; ks++) {
            bf16x8 kf0 = *(const bf16x8*)((const char*)k_lds + lr * 1024 + (((ks * 4 + g) ^ (lr & 7)) * 16));
            s0 = MFMA16(qf[ks], kf0, s0);
            int row1 = 16 + lr;
            bf16x8 kf1 = *(const bf16x8*)((const char*)k_lds + row1 * 1024 + (((ks * 4 + g) ^ (row1 & 7)) * 16));
            s1 = MFMA16(qf[ks], kf1, s1);
        }
        // row max over j (cols = lr within 16-lane group)
        f32x4 mt;
#pragma unroll
        for (int r = 0; r < 4; r++) mt[r] = fmaxf(s0[r], s1[r]);
#pragma unroll
        for (int msk = 1; msk <= 8; msk <<= 1) {
#pragma unroll
            for (int r = 0; r < 4; r++) mt[r] = fmaxf(mt[r], __shfl_xor(mt[r], msk));
        }
        int inc = (mt[0] > mst[0]) || (mt[1] > mst[1]) || (mt[2] > mst[2]) || (mt[3] > mst[3]);
        if (__any(inc)) {   // rescale only when running max grows (else P<=1 with old max)
            f32x4 alpha;
#pragma unroll
            for (int r = 0; r < 4; r++) {
                float mn = fmaxf(mst[r], mt[r]);
                alpha[r] = exp2f(mst[r] - mn);
                mst[r] = mn;
                lst[r] *= alpha[r];
            }
            int src = (lr >> 2) << 4;
            float a0 = __shfl(alpha[0], src), a1 = __shfl(alpha[1], src);
            float a2 = __shfl(alpha[2], src), a3 = __shfl(alpha[3], src);
            int rr = lr & 3;
            float ac = rr == 0 ? a0 : rr == 1 ? a1 : rr == 2 ? a2 : a3;
#pragma unroll
            for (int i = 0; i < 32; i++) {
#pragma unroll
                for (int r = 0; r < 4; r++) oacc[i][r] *= ac;
            }
        }
        f32x4 p0, p1, rsum;
#pragma unroll
        for (int r = 0; r < 4; r++) {
            p0[r] = exp2f(s0[r] - mst[r]);
            p1[r] = exp2f(s1[r] - mst[r]);
            rsum[r] = p0[r] + p1[r];
        }
#pragma unroll
        for (int msk = 1; msk <= 8; msk <<= 1) {
#pragma unroll
            for (int r = 0; r < 4; r++) rsum[r] += __shfl_xor(rsum[r], msk);
        }
#pragma unroll
        for (int r = 0; r < 4; r++) lst[r] += rsum[r];

        // P -> LDS (wave-private), then O^T += V * P^T
#pragma unroll
        for (int r = 0; r < 4; r++) {
            int i = g * 4 + r;
            int ja = lr;
            *(unsigned short*)((char*)p_lds[w] + i * 128 + (((ja >> 3) ^ (i & 7)) * 16) + (ja & 7) * 2) = f2bf(p0[r]);
            int jb = 16 + lr;
            *(unsigned short*)((char*)p_lds[w] + i * 128 + (((jb >> 3) ^ (i & 7)) * 16) + (jb & 7) * 2) = f2bf(p1[r]);
        }
        bf16x8 pf = *(const bf16x8*)((const char*)p_lds[w] + lr * 128 + ((g ^ (lr & 7)) * 16));
#pragma unroll
        for (int ct = 0; ct < 32; ct++) {
            int row = ct * 16 + lr;
            bf16x8 vf = *(const bf16x8*)((const char*)v_lds + row * 80 + g * 16);
            oacc[ct] = MFMA16(vf, pf, oacc[ct]);
        }
    }

    // epilogue: divide by l, write ao[b][i][c]
    int src = (lr >> 2) << 4;
    float l0 = __shfl(lst[0], src), l1 = __shfl(lst[1], src);
    float l2 = __shfl(lst[2], src), l3 = __shfl(lst[3], src);
    int rr = lr & 3;
    float lc = rr == 0 ? l0 : rr == 1 ? l1 : rr == 2 ? l2 : l3;
    float inv = 1.0f / lc;
    unsigned short* aob = ao + ((size_t)b * SP_N + blockIdx.x * 64 + w * 16 + lr) * C_N;
#pragma unroll
    for (int ct = 0; ct < 32; ct++) {
        int c0 = ct * 16 + g * 4;
        ushort4 o4;
        o4.x = f2bf(oacc[ct][0] * inv);
        o4.y = f2bf(oacc[ct][1] * inv);
        o4.z = f2bf(oacc[ct][2] * inv);
        o4.w = f2bf(oacc[ct][3] * inv);
        *(ushort4*)(aob + c0) = o4;
    }
}

extern "C" void kernel_launch(void* const* d_in, const int* in_sizes, int n_in,
                              void* d_out, int out_size, void* d_ws, size_t ws_size,
                              hipStream_t stream) {
    const float* x   = (const float*)d_in[0];
    const float* gam = (const float*)d_in[1];
    const float* bet = (const float*)d_in[2];
    const float* wq  = (const float*)d_in[3];
    const float* bq  = (const float*)d_in[4];
    const float* wk  = (const float*)d_in[5];
    const float* bk  = (const float*)d_in[6];
    const float* wv  = (const float*)d_in[7];
    const float* bv  = (const float*)d_in[8];
    const float* wp  = (const float*)d_in[9];
    const float* bp  = (const float*)d_in[10];

    char* ws = (char*)d_ws;
    const size_t SZ = (size_t)B_N * SP_N * C_N * 2;   // 16 MiB per bf16 tensor
    unsigned short* h_t = (unsigned short*)(ws);
    unsigned short* q_t = (unsigned short*)(ws + SZ);
    unsigned short* k_t = (unsigned short*)(ws + 2 * SZ);
    unsigned short* v_m = (unsigned short*)(ws + 3 * SZ);
    unsigned short* ao  = h_t;                        // h_t dead after V gemm; reuse
    unsigned short* wbf = (unsigned short*)(ws + 4 * SZ);
    unsigned short* wq_b = wbf;
    unsigned short* wk_b = wbf + 262144;
    unsigned short* wv_b = wbf + 2 * 262144;
    unsigned short* wp_b = wbf + 3 * 262144;

    const float qs = 0.044194173824159216f * 1.4426950408889634f;  // C^-0.5 * log2(e)

    wconv<<<dim3(256, 4), 256, 0, stream>>>(wq, wk, wv, wp, wbf);
    gn_kernel<<<dim3(128), 512, 0, stream>>>(x, gam, bet, h_t);
    gemm_nt<0><<<dim3(32, 4, 4), 256, 0, stream>>>(h_t, wq_b, q_t, bq, nullptr, qs);
    gemm_nt<1><<<dim3(32, 4, 4), 256, 0, stream>>>(h_t, wk_b, k_t, bk, nullptr, 1.f);
    gemm_nt<2><<<dim3(4, 32, 4), 256, 0, stream>>>(wv_b, h_t, v_m, bv, nullptr, 1.f);
    attn_kernel<<<dim3(64, 4), 256, 0, stream>>>(q_t, k_t, v_m, ao);
    gemm_nt<3><<<dim3(4, 32, 4), 256, 0, stream>>>(wp_b, ao, d_out, bp, x, 1.f);
}

// Round 3
// 841.785 us; speedup vs baseline: 1.4080x; 1.4080x over previous
//
#include <hip/hip_runtime.h>
#include <stdint.h>

#define B_N 4
#define C_N 512
#define SP_N 4096   // H*W
#define NG 32
#define CPG 16
#define EPS_ 1e-6f

using bf16x8 = __attribute__((ext_vector_type(8))) __bf16;
using f32x4  = __attribute__((ext_vector_type(4))) float;

#define MFMA16(a, b, c) __builtin_amdgcn_mfma_f32_16x16x32_bf16(a, b, c, 0, 0, 0)

#define GLOAD16(gsrc, ldst) \
    __builtin_amdgcn_global_load_lds( \
        (const __attribute__((address_space(1))) unsigned int*)(gsrc), \
        (__attribute__((address_space(3))) unsigned int*)(ldst), 16, 0, 0)

__device__ __forceinline__ unsigned short f2bf(float f) {
    union { float f; unsigned u; } v; v.f = f;
    unsigned r = v.u + 0x7FFFu + ((v.u >> 16) & 1u);
    return (unsigned short)(r >> 16);
}
__device__ __forceinline__ float bf2f(unsigned short s) {
    union { unsigned u; float f; } v; v.u = ((unsigned)s) << 16;
    return v.f;
}

// ---------------- weight fp32 -> bf16 ----------------
__global__ void wconv(const float* __restrict__ a, const float* __restrict__ b,
                      const float* __restrict__ c, const float* __restrict__ d,
                      unsigned short* __restrict__ dst) {
    int m = blockIdx.y;
    const float* src = m == 0 ? a : m == 1 ? b : m == 2 ? c : d;
    int i = blockIdx.x * 256 + threadIdx.x;          // 0..65535 float4s
    float4 v = ((const float4*)src)[i];
    ushort4 o;
    o.x = f2bf(v.x); o.y = f2bf(v.y); o.z = f2bf(v.z); o.w = f2bf(v.w);
    ((ushort4*)(dst + (size_t)m * 262144))[i] = o;
}

// ---------------- GroupNorm -> h^T [B][N][C] bf16 ----------------
__global__ __launch_bounds__(512) void gn_kernel(const float* __restrict__ x,
        const float* __restrict__ gamma, const float* __restrict__ beta,
        unsigned short* __restrict__ h_t) {
    int blk = blockIdx.x;            // 0..127
    int b = blk >> 5, g = blk & 31;
    const float* xg = x + ((size_t)(b * C_N + g * CPG)) * SP_N;  // 16 contiguous channels
    int t = threadIdx.x;

    float s = 0.f, ss = 0.f;
    const float4* xv = (const float4*)xg;
    for (int i = t; i < (CPG * SP_N) / 4; i += 512) {
        float4 v = xv[i];
        s  += v.x + v.y + v.z + v.w;
        ss += v.x * v.x + v.y * v.y + v.z * v.z + v.w * v.w;
    }
    for (int m = 32; m; m >>= 1) { s += __shfl_xor(s, m); ss += __shfl_xor(ss, m); }
    __shared__ float rs[8], rss[8], stats[2];
    int wid = t >> 6;
    if ((t & 63) == 0) { rs[wid] = s; rss[wid] = ss; }
    __syncthreads();
    if (t == 0) {
        float a = 0.f, q = 0.f;
        for (int i = 0; i < 8; i++) { a += rs[i]; q += rss[i]; }
        float mean = a / (float)(CPG * SP_N);
        float var  = q / (float)(CPG * SP_N) - mean * mean;
        stats[0] = mean;
        stats[1] = rsqrtf(var + EPS_);
    }
    __shared__ float gam[CPG], bet[CPG];
    if (t < CPG) { gam[t] = gamma[g * CPG + t]; bet[t] = beta[g * CPG + t]; }
    __syncthreads();
    float mean = stats[0], rstd = stats[1];

    __shared__ unsigned short tile[CPG][130];
    unsigned short* hb = h_t + (size_t)b * SP_N * C_N;
    for (int n0 = 0; n0 < SP_N; n0 += 128) {
        __syncthreads();   // protect tile from previous write phase
#pragma unroll
        for (int p = 0; p < 4; p++) {
            int cc = p * 4 + (t >> 7);
            int nn = t & 127;
            float v = xg[(size_t)cc * SP_N + n0 + nn];
            v = (v - mean) * rstd * gam[cc] + bet[cc];
            tile[cc][nn] = f2bf(v);
        }
        __syncthreads();
#pragma unroll
        for (int p = 0; p < 4; p++) {
            int idx = p * 512 + t;
            int cc = idx & 15, nn = idx >> 4;
            hb[(size_t)(n0 + nn) * C_N + g * CPG + cc] = tile[cc][nn];
        }
    }
}

// ---------------- generic NT GEMM: out[m][n] = sum_k A[m][k]*B[n][k] + epilogue ----
// MODE 0: Q  (bias[n], *qs, bf16 out)   A=h_t[b], B=wq
// MODE 1: K  (bias[n], bf16 out)        A=h_t[b], B=wk
// MODE 2: V  (bias[m], bf16 out)        A=wv,     B=h_t[b]
// MODE 3: P  (bias[m]+resid, f32 out)   A=wp,     B=ao[b]
template<int MODE>
__global__ __launch_bounds__(256) void gemm_nt(
        const unsigned short* __restrict__ Ab,
        const unsigned short* __restrict__ Bb,
        void* __restrict__ outp,
        const float* __restrict__ bias,
        const float* __restrict__ resid,
        float qs) {
    __shared__ unsigned short at[128 * 64], bt[128 * 64];
    const int z = blockIdx.z;
    const size_t boff = (size_t)z * SP_N * C_N;
    const unsigned short* A;
    const unsigned short* Bm;
    int ldo;
    if (MODE <= 1) { A = Ab + boff; Bm = Bb; ldo = C_N; }
    else           { A = Ab;        Bm = Bb + boff; ldo = SP_N; }
    const int m0 = blockIdx.x * 128, n0 = blockIdx.y * 128;
    const int t = threadIdx.x;
    const int w = t >> 6, l = t & 63;
    const int wr = w >> 1, wc = w & 1;
    const int g = l >> 4, lr = l & 15;

    const f32x4 fz = {0.f, 0.f, 0.f, 0.f};
    f32x4 acc[4][4];
#pragma unroll
    for (int i = 0; i < 4; i++)
#pragma unroll
        for (int j = 0; j < 4; j++) acc[i][j] = fz;

    for (int k0 = 0; k0 < 512; k0 += 64) {
        __syncthreads();
#pragma unroll
        for (int r = 0; r < 4; r++) {
            int chunk = r * 256 + t;
            int row = chunk >> 3, ck = chunk & 7;
            uint4 da = *(const uint4*)(A + (size_t)(m0 + row) * 512 + k0 + ck * 8);
            *(uint4*)((char*)at + row * 128 + ((ck ^ (row & 7)) * 16)) = da;
            uint4 db = *(const uint4*)(Bm + (size_t)(n0 + row) * 512 + k0 + ck * 8);
            *(uint4*)((char*)bt + row * 128 + ((ck ^ (row & 7)) * 16)) = db;
        }
        __syncthreads();
#pragma unroll
        for (int ks = 0; ks < 2; ks++) {
            bf16x8 af[4], bfr[4];
#pragma unroll
            for (int mi = 0; mi < 4; mi++) {
                int row = wr * 64 + mi * 16 + lr;
                af[mi] = *(const bf16x8*)((const char*)at + row * 128 + (((ks * 4 + g) ^ (row & 7)) * 16));
            }
#pragma unroll
            for (int ni = 0; ni < 4; ni++) {
                int row = wc * 64 + ni * 16 + lr;
                bfr[ni] = *(const bf16x8*)((const char*)bt + row * 128 + (((ks * 4 + g) ^ (row & 7)) * 16));
            }
#pragma unroll
            for (int mi = 0; mi < 4; mi++)
#pragma unroll
                for (int ni = 0; ni < 4; ni++)
                    acc[mi][ni] = MFMA16(af[mi], bfr[ni], acc[mi][ni]);
        }
    }
#pragma unroll
    for (int mi = 0; mi < 4; mi++) {
#pragma unroll
        for (int ni = 0; ni < 4; ni++) {
            int col  = n0 + wc * 64 + ni * 16 + lr;
            int rowb = m0 + wr * 64 + mi * 16 + g * 4;
#pragma unroll
            for (int r = 0; r < 4; r++) {
                int row = rowb + r;
                float vv = acc[mi][ni][r];
                size_t oi = boff + (size_t)row * ldo + col;
                if (MODE == 0) {
                    vv = (vv + bias[col]) * qs;
                    ((unsigned short*)outp)[oi] = f2bf(vv);
                } else if (MODE == 1) {
                    vv += bias[col];
                    ((unsigned short*)outp)[oi] = f2bf(vv);
                } else if (MODE == 2) {
                    vv += bias[row];
                    ((unsigned short*)outp)[oi] = f2bf(vv);
                } else {
                    vv += bias[row] + resid[oi];
                    ((float*)outp)[oi] = vv;
                }
            }
        }
    }
}

// ---------------- flash attention (KV-split x2) ----------------
// q_t,k_t: [B][N][C] bf16 (q pre-scaled by c^-0.5 * log2e); v: [B][C][N] bf16
// Per split s: writes UNNORMALIZED O_s bf16 [B][N][C] plus m_s,l_s f32 [B][N].
__global__ __launch_bounds__(256, 2) void attn_kernel(
        const unsigned short* __restrict__ qt,
        const unsigned short* __restrict__ kt,
        const unsigned short* __restrict__ vm,
        unsigned short* __restrict__ o0,
        unsigned short* __restrict__ o1,
        float* __restrict__ marr,
        float* __restrict__ larr) {
    __shared__ unsigned short k_lds[32 * 512];     // [j][c], swizzled (16B chunk ^ (row&7))
    __shared__ unsigned short v_lds[512 * 40];     // [c][j], row stride 80B
    __shared__ unsigned short p_lds[4][16 * 32];   // per wave [i][j], 64B rows, 2-bit XOR

    const int b = blockIdx.y;
    const int s = blockIdx.z;
    const int t = threadIdx.x;
    const int w = t >> 6;
    const int l = t & 63;
    const int g = l >> 4;
    const int lr = l & 15;

    unsigned short* outp = s == 0 ? o0 : o1;
    const int j_beg = s * (SP_N / 2);

    const unsigned short* qb = qt + ((size_t)b * SP_N + blockIdx.x * 64 + w * 16) * C_N;
    const unsigned short* kb = kt + (size_t)b * SP_N * C_N;
    const unsigned short* vb = vm + (size_t)b * C_N * SP_N;

    bf16x8 qf[16];
#pragma unroll
    for (int ks = 0; ks < 16; ks++)
        qf[ks] = *(const bf16x8*)(qb + (size_t)lr * C_N + ks * 32 + g * 8);

    const f32x4 fz = {0.f, 0.f, 0.f, 0.f};
    f32x4 oacc[32];
#pragma unroll
    for (int i = 0; i < 32; i++) oacc[i] = fz;
    f32x4 mst = {-1e30f, -1e30f, -1e30f, -1e30f};
    f32x4 lst = {0.f, 0.f, 0.f, 0.f};

    for (int j0 = j_beg; j0 < j_beg + SP_N / 2; j0 += 32) {
        __syncthreads();   // all waves done reading LDS from previous iter

        // --- K tile [32][512] via global_load_lds DMA, pre-swizzled source ---
        // dest chunk p of row holds global chunk p^(row&7); lane l -> dest chunk l
#pragma unroll
        for (int r = 0; r < 8; r++) {
            int row = w * 8 + r;
            const unsigned short* src = kb + (size_t)(j0 + row) * C_N + (l ^ (row & 7)) * 8;
            GLOAD16(src, (char*)k_lds + row * 1024);
        }
        // --- V tile [512][32] reg-staged: issue all loads, then all writes ---
        uint4 vdat[8];
#pragma unroll
        for (int r = 0; r < 8; r++) {
            int chunk = r * 256 + t;
            int c = chunk >> 2, jc = chunk & 3;
            vdat[r] = *(const uint4*)(vb + (size_t)c * SP_N + j0 + jc * 8);
        }
#pragma unroll
        for (int r = 0; r < 8; r++) {
            int chunk = r * 256 + t;
            int c = chunk >> 2, jc = chunk & 3;
            *(uint4*)((char*)v_lds + c * 80 + jc * 16) = vdat[r];
        }
        __syncthreads();   // drains vmcnt(0): DMA K + V writes complete

        // S = Q K^T  (exp2 domain, scale folded into q)
        f32x4 s0 = fz, s1 = fz;
#pragma unroll
        for (int ks = 0; ks < 16; ks++) {
            bf16x8 kf0 = *(const bf16x8*)((const char*)k_lds + lr * 1024 + (((ks * 4 + g) ^ (lr & 7)) * 16));
            s0 = MFMA16(qf[ks], kf0, s0);
            int row1 = 16 + lr;
            bf16x8 kf1 = *(const bf16x8*)((const char*)k_lds + row1 * 1024 + (((ks * 4 + g) ^ (row1 & 7)) * 16));
            s1 = MFMA16(qf[ks], kf1, s1);
        }
        // row max over j (cols = lr within 16-lane group)
        f32x4 mt;
#pragma unroll
        for (int r = 0; r < 4; r++) mt[r] = fmaxf(s0[r], s1[r]);
#pragma unroll
        for (int msk = 1; msk <= 8; msk <<= 1) {
#pragma unroll
            for (int r = 0; r < 4; r++) mt[r] = fmaxf(mt[r], __shfl_xor(mt[r], msk));
        }
        int inc = (mt[0] > mst[0]) || (mt[1] > mst[1]) || (mt[2] > mst[2]) || (mt[3] > mst[3]);
        if (__any(inc)) {   // rescale only when running max grows (else P<=1 with old max)
            f32x4 alpha;
#pragma unroll
            for (int r = 0; r < 4; r++) {
                float mn = fmaxf(mst[r], mt[r]);
                alpha[r] = exp2f(mst[r] - mn);
                mst[r] = mn;
                lst[r] *= alpha[r];
            }
            int src = (lr >> 2) << 4;
            float a0 = __shfl(alpha[0], src), a1 = __shfl(alpha[1], src);
            float a2 = __shfl(alpha[2], src), a3 = __shfl(alpha[3], src);
            int rr = lr & 3;
            float ac = rr == 0 ? a0 : rr == 1 ? a1 : rr == 2 ? a2 : a3;
#pragma unroll
            for (int i = 0; i < 32; i++) {
#pragma unroll
                for (int r = 0; r < 4; r++) oacc[i][r] *= ac;
            }
        }
        f32x4 p0, p1, rsum;
#pragma unroll
        for (int r = 0; r < 4; r++) {
            p0[r] = exp2f(s0[r] - mst[r]);
            p1[r] = exp2f(s1[r] - mst[r]);
            rsum[r] = p0[r] + p1[r];
        }
#pragma unroll
        for (int msk = 1; msk <= 8; msk <<= 1) {
#pragma unroll
            for (int r = 0; r < 4; r++) rsum[r] += __shfl_xor(rsum[r], msk);
        }
#pragma unroll
        for (int r = 0; r < 4; r++) lst[r] += rsum[r];

        // P -> LDS (wave-private, 64B rows, chunk XOR (i>>1)&3), then O^T += V P^T
#pragma unroll
        for (int r = 0; r < 4; r++) {
            int i = g * 4 + r;
            int ja = lr;
            *(unsigned short*)((char*)p_lds[w] + i * 64 + (((ja >> 3) ^ ((i >> 1) & 3)) * 16) + (ja & 7) * 2) = f2bf(p0[r]);
            int jb = 16 + lr;
            *(unsigned short*)((char*)p_lds[w] + i * 64 + (((jb >> 3) ^ ((i >> 1) & 3)) * 16) + (jb & 7) * 2) = f2bf(p1[r]);
        }
        bf16x8 pf = *(const bf16x8*)((const char*)p_lds[w] + lr * 64 + ((g ^ ((lr >> 1) & 3)) * 16));
#pragma unroll
        for (int ct = 0; ct < 32; ct++) {
            int row = ct * 16 + lr;
            bf16x8 vf = *(const bf16x8*)((const char*)v_lds + row * 80 + g * 16);
            oacc[ct] = MFMA16(vf, pf, oacc[ct]);
        }
    }

    // epilogue: write UNNORMALIZED O_s [b][i][c] bf16 + per-row m,l
    unsigned short* aob = outp + ((size_t)b * SP_N + blockIdx.x * 64 + w * 16 + lr) * C_N;
#pragma unroll
    for (int ct = 0; ct < 32; ct++) {
        int c0 = ct * 16 + g * 4;
        ushort4 o4;
        o4.x = f2bf(oacc[ct][0]);
        o4.y = f2bf(oacc[ct][1]);
        o4.z = f2bf(oacc[ct][2]);
        o4.w = f2bf(oacc[ct][3]);
        *(ushort4*)(aob + c0) = o4;
    }
    if (lr == 0) {
        int base = (s * B_N + b) * SP_N + blockIdx.x * 64 + w * 16 + g * 4;
#pragma unroll
        for (int r = 0; r < 4; r++) {
            marr[base + r] = mst[r];
            larr[base + r] = lst[r];
        }
    }
}

// ---------------- combine 2 KV-splits ----------------
__global__ __launch_bounds__(256) void attn_combine(
        const unsigned short* __restrict__ o0,
        const unsigned short* __restrict__ o1,
        const float* __restrict__ marr,
        const float* __restrict__ larr,
        unsigned short* __restrict__ ao) {
    const int w = threadIdx.x >> 6, l = threadIdx.x & 63;
    const size_t row = (size_t)blockIdx.x * 4 + w;   // b*N + n, 0..16383
    float m0 = marr[row], m1 = marr[B_N * SP_N + row];
    float l0 = larr[row], l1 = larr[B_N * SP_N + row];
    float m = fmaxf(m0, m1);
    float w0 = exp2f(m0 - m), w1 = exp2f(m1 - m);
    float den = w0 * l0 + w1 * l1;
    float a0 = w0 / den, a1 = w1 / den;
    uint4 u0 = *(const uint4*)(o0 + row * C_N + l * 8);
    uint4 u1 = *(const uint4*)(o1 + row * C_N + l * 8);
    const unsigned short* s0p = (const unsigned short*)&u0;
    const unsigned short* s1p = (const unsigned short*)&u1;
    unsigned short r8[8];
#pragma unroll
    for (int i = 0; i < 8; i++)
        r8[i] = f2bf(a0 * bf2f(s0p[i]) + a1 * bf2f(s1p[i]));
    *(uint4*)(ao + row * C_N + l * 8) = *(const uint4*)r8;
}

extern "C" void kernel_launch(void* const* d_in, const int* in_sizes, int n_in,
                              void* d_out, int out_size, void* d_ws, size_t ws_size,
                              hipStream_t stream) {
    const float* x   = (const float*)d_in[0];
    const float* gam = (const float*)d_in[1];
    const float* bet = (const float*)d_in[2];
    const float* wq  = (const float*)d_in[3];
    const float* bq  = (const float*)d_in[4];
    const float* wk  = (const float*)d_in[5];
    const float* bk  = (const float*)d_in[6];
    const float* wv  = (const float*)d_in[7];
    const float* bv  = (const float*)d_in[8];
    const float* wp  = (const float*)d_in[9];
    const float* bp  = (const float*)d_in[10];

    char* ws = (char*)d_ws;
    const size_t SZ = (size_t)B_N * SP_N * C_N * 2;   // 16 MiB per bf16 tensor
    unsigned short* h_t = (unsigned short*)(ws);
    unsigned short* q_t = (unsigned short*)(ws + SZ);
    unsigned short* k_t = (unsigned short*)(ws + 2 * SZ);
    unsigned short* v_m = (unsigned short*)(ws + 3 * SZ);
    unsigned short* wbf = (unsigned short*)(ws + 4 * SZ);
    unsigned short* wq_b = wbf;
    unsigned short* wk_b = wbf + 262144;
    unsigned short* wv_b = wbf + 2 * 262144;
    unsigned short* wp_b = wbf + 3 * 262144;
    float* marr = (float*)(ws + 4 * SZ + 4 * 524288);          // [2][B][N]
    float* larr = marr + 2 * B_N * SP_N;

    unsigned short* o0 = h_t;                       // h_t dead after V gemm
    unsigned short* o1 = (unsigned short*)d_out;    // 16MB of d_out's 32MB as scratch
    unsigned short* ao = q_t;                       // q_t dead after attn

    const float qs = 0.044194173824159216f * 1.4426950408889634f;  // C^-0.5 * log2(e)

    wconv<<<dim3(256, 4), 256, 0, stream>>>(wq, wk, wv, wp, wbf);
    gn_kernel<<<dim3(128), 512, 0, stream>>>(x, gam, bet, h_t);
    gemm_nt<0><<<dim3(32, 4, 4), 256, 0, stream>>>(h_t, wq_b, q_t, bq, nullptr, qs);
    gemm_nt<1><<<dim3(32, 4, 4), 256, 0, stream>>>(h_t, wk_b, k_t, bk, nullptr, 1.f);
    gemm_nt<2><<<dim3(4, 32, 4), 256, 0, stream>>>(wv_b, h_t, v_m, bv, nullptr, 1.f);
    attn_kernel<<<dim3(64, 4, 2), 256, 0, stream>>>(q_t, k_t, v_m, o0, o1, marr, larr);
    attn_combine<<<dim3(B_N * SP_N / 4), 256, 0, stream>>>(o0, o1, marr, larr, ao);
    gemm_nt<3><<<dim3(4, 32, 4), 256, 0, stream>>>(wp_b, ao, d_out, bp, x, 1.f);
}

// Round 4
// 703.441 us; speedup vs baseline: 1.6849x; 1.1967x over previous
//
#include <hip/hip_runtime.h>
#include <stdint.h>

#define B_N 4
#define C_N 512
#define SP_N 4096   // H*W
#define NG 32
#define CPG 16
#define EPS_ 1e-6f

using bf16x8 = __attribute__((ext_vector_type(8))) __bf16;
using f32x4  = __attribute__((ext_vector_type(4))) float;

#define MFMA16(a, b, c) __builtin_amdgcn_mfma_f32_16x16x32_bf16(a, b, c, 0, 0, 0)

#define GLOAD16(gsrc, ldst) \
    __builtin_amdgcn_global_load_lds( \
        (const __attribute__((address_space(1))) unsigned int*)(gsrc), \
        (__attribute__((address_space(3))) unsigned int*)(ldst), 16, 0, 0)

__device__ __forceinline__ unsigned short f2bf(float f) {
    union { float f; unsigned u; } v; v.f = f;
    unsigned r = v.u + 0x7FFFu + ((v.u >> 16) & 1u);
    return (unsigned short)(r >> 16);
}
__device__ __forceinline__ float bf2f(unsigned short s) {
    union { unsigned u; float f; } v; v.u = ((unsigned)s) << 16;
    return v.f;
}

// ---------------- weight fp32 -> bf16 ----------------
__global__ void wconv(const float* __restrict__ a, const float* __restrict__ b,
                      const float* __restrict__ c, const float* __restrict__ d,
                      unsigned short* __restrict__ dst) {
    int m = blockIdx.y;
    const float* src = m == 0 ? a : m == 1 ? b : m == 2 ? c : d;
    int i = blockIdx.x * 256 + threadIdx.x;          // 0..65535 float4s
    float4 v = ((const float4*)src)[i];
    ushort4 o;
    o.x = f2bf(v.x); o.y = f2bf(v.y); o.z = f2bf(v.z); o.w = f2bf(v.w);
    ((ushort4*)(dst + (size_t)m * 262144))[i] = o;
}

// ---------------- GroupNorm -> h^T [B][N][C] bf16 ----------------
__global__ __launch_bounds__(512) void gn_kernel(const float* __restrict__ x,
        const float* __restrict__ gamma, const float* __restrict__ beta,
        unsigned short* __restrict__ h_t) {
    int blk = blockIdx.x;            // 0..127
    int b = blk >> 5, g = blk & 31;
    const float* xg = x + ((size_t)(b * C_N + g * CPG)) * SP_N;  // 16 contiguous channels
    int t = threadIdx.x;

    float s = 0.f, ss = 0.f;
    const float4* xv = (const float4*)xg;
    for (int i = t; i < (CPG * SP_N) / 4; i += 512) {
        float4 v = xv[i];
        s  += v.x + v.y + v.z + v.w;
        ss += v.x * v.x + v.y * v.y + v.z * v.z + v.w * v.w;
    }
    for (int m = 32; m; m >>= 1) { s += __shfl_xor(s, m); ss += __shfl_xor(ss, m); }
    __shared__ float rs[8], rss[8], stats[2];
    int wid = t >> 6;
    if ((t & 63) == 0) { rs[wid] = s; rss[wid] = ss; }
    __syncthreads();
    if (t == 0) {
        float a = 0.f, q = 0.f;
        for (int i = 0; i < 8; i++) { a += rs[i]; q += rss[i]; }
        float mean = a / (float)(CPG * SP_N);
        float var  = q / (float)(CPG * SP_N) - mean * mean;
        stats[0] = mean;
        stats[1] = rsqrtf(var + EPS_);
    }
    __shared__ float gam[CPG], bet[CPG];
    if (t < CPG) { gam[t] = gamma[g * CPG + t]; bet[t] = beta[g * CPG + t]; }
    __syncthreads();
    float mean = stats[0], rstd = stats[1];

    __shared__ unsigned short tile[CPG][130];
    unsigned short* hb = h_t + (size_t)b * SP_N * C_N;
    for (int n0 = 0; n0 < SP_N; n0 += 128) {
        __syncthreads();   // protect tile from previous write phase
#pragma unroll
        for (int p = 0; p < 4; p++) {
            int cc = p * 4 + (t >> 7);
            int nn = t & 127;
            float v = xg[(size_t)cc * SP_N + n0 + nn];
            v = (v - mean) * rstd * gam[cc] + bet[cc];
            tile[cc][nn] = f2bf(v);
        }
        __syncthreads();
#pragma unroll
        for (int p = 0; p < 4; p++) {
            int idx = p * 512 + t;
            int cc = idx & 15, nn = idx >> 4;
            hb[(size_t)(n0 + nn) * C_N + g * CPG + cc] = tile[cc][nn];
        }
    }
}

// ---------------- generic NT GEMM: out[m][n] = sum_k A[m][k]*B[n][k] + epilogue ----
// MODE 0: Q  (bias[n], *qs, bf16 out)   A=h_t[b], B=wq
// MODE 1: K  (bias[n], bf16 out)        A=h_t[b], B=wk
// MODE 2: V  (bias[m], bf16 out, BLOCKED [N/32][C][32])  A=wv, B=h_t[b]
// MODE 3: P  (bias[m]+resid, f32 out)   A=wp,     B=ao[b]
template<int MODE>
__global__ __launch_bounds__(256) void gemm_nt(
        const unsigned short* __restrict__ Ab,
        const unsigned short* __restrict__ Bb,
        void* __restrict__ outp,
        const float* __restrict__ bias,
        const float* __restrict__ resid,
        float qs) {
    __shared__ unsigned short at[128 * 64], bt[128 * 64];
    const int z = blockIdx.z;
    const size_t boff = (size_t)z * SP_N * C_N;
    const unsigned short* A;
    const unsigned short* Bm;
    int ldo;
    if (MODE <= 1) { A = Ab + boff; Bm = Bb; ldo = C_N; }
    else           { A = Ab;        Bm = Bb + boff; ldo = SP_N; }
    const int m0 = blockIdx.x * 128, n0 = blockIdx.y * 128;
    const int t = threadIdx.x;
    const int w = t >> 6, l = t & 63;
    const int wr = w >> 1, wc = w & 1;
    const int g = l >> 4, lr = l & 15;

    const f32x4 fz = {0.f, 0.f, 0.f, 0.f};
    f32x4 acc[4][4];
#pragma unroll
    for (int i = 0; i < 4; i++)
#pragma unroll
        for (int j = 0; j < 4; j++) acc[i][j] = fz;

    for (int k0 = 0; k0 < 512; k0 += 64) {
        __syncthreads();
#pragma unroll
        for (int r = 0; r < 4; r++) {
            int chunk = r * 256 + t;
            int row = chunk >> 3, ck = chunk & 7;
            uint4 da = *(const uint4*)(A + (size_t)(m0 + row) * 512 + k0 + ck * 8);
            *(uint4*)((char*)at + row * 128 + ((ck ^ (row & 7)) * 16)) = da;
            uint4 db = *(const uint4*)(Bm + (size_t)(n0 + row) * 512 + k0 + ck * 8);
            *(uint4*)((char*)bt + row * 128 + ((ck ^ (row & 7)) * 16)) = db;
        }
        __syncthreads();
#pragma unroll
        for (int ks = 0; ks < 2; ks++) {
            bf16x8 af[4], bfr[4];
#pragma unroll
            for (int mi = 0; mi < 4; mi++) {
                int row = wr * 64 + mi * 16 + lr;
                af[mi] = *(const bf16x8*)((const char*)at + row * 128 + (((ks * 4 + g) ^ (row & 7)) * 16));
            }
#pragma unroll
            for (int ni = 0; ni < 4; ni++) {
                int row = wc * 64 + ni * 16 + lr;
                bfr[ni] = *(const bf16x8*)((const char*)bt + row * 128 + (((ks * 4 + g) ^ (row & 7)) * 16));
            }
#pragma unroll
            for (int mi = 0; mi < 4; mi++)
#pragma unroll
                for (int ni = 0; ni < 4; ni++)
                    acc[mi][ni] = MFMA16(af[mi], bfr[ni], acc[mi][ni]);
        }
    }
#pragma unroll
    for (int mi = 0; mi < 4; mi++) {
#pragma unroll
        for (int ni = 0; ni < 4; ni++) {
            int col  = n0 + wc * 64 + ni * 16 + lr;
            int rowb = m0 + wr * 64 + mi * 16 + g * 4;
#pragma unroll
            for (int r = 0; r < 4; r++) {
                int row = rowb + r;
                float vv = acc[mi][ni][r];
                if (MODE == 0) {
                    size_t oi = boff + (size_t)row * ldo + col;
                    vv = (vv + bias[col]) * qs;
                    ((unsigned short*)outp)[oi] = f2bf(vv);
                } else if (MODE == 1) {
                    size_t oi = boff + (size_t)row * ldo + col;
                    vv += bias[col];
                    ((unsigned short*)outp)[oi] = f2bf(vv);
                } else if (MODE == 2) {
                    // blocked: [j>>5][c][j&31]
                    size_t oi = boff + (size_t)(col >> 5) * (C_N * 32) + row * 32 + (col & 31);
                    vv += bias[row];
                    ((unsigned short*)outp)[oi] = f2bf(vv);
                } else {
                    size_t oi = boff + (size_t)row * ldo + col;
                    vv += bias[row] + resid[oi];
                    ((float*)outp)[oi] = vv;
                }
            }
        }
    }
}

// ---------------- flash attention (KV-split x2, XCD-affine) ----------------
// q_t,k_t: [B][N][C] bf16 (q pre-scaled by c^-0.5 * log2e)
// v: BLOCKED [B][N/32][C][32] bf16
// 1-D grid of 512: bid&7 = (b<<1)|s  -> all blocks sharing a K/V stream land
// on one XCD (dispatch round-robins bid%8 across XCDs); bid>>3 = q-tile.
// Per split s: writes UNNORMALIZED O_s bf16 [B][N][C] plus m_s,l_s f32 [B][N].
__global__ __launch_bounds__(256, 2) void attn_kernel(
        const unsigned short* __restrict__ qt,
        const unsigned short* __restrict__ kt,
        const unsigned short* __restrict__ vm,
        unsigned short* __restrict__ o0,
        unsigned short* __restrict__ o1,
        float* __restrict__ marr,
        float* __restrict__ larr) {
    __shared__ unsigned short k_lds[32 * 512];     // [j][c], swizzled (16B chunk ^ (row&7))
    __shared__ unsigned short v_lds[512 * 40];     // [c][j], row stride 80B
    __shared__ unsigned short p_lds[4][16 * 32];   // per wave [i][j], 64B rows, 2-bit XOR

    const int bid = blockIdx.x;
    const int bs = bid & 7;
    const int qtile = bid >> 3;
    const int b = bs >> 1;
    const int s = bs & 1;
    const int t = threadIdx.x;
    const int w = t >> 6;
    const int l = t & 63;
    const int g = l >> 4;
    const int lr = l & 15;

    unsigned short* outp = s == 0 ? o0 : o1;
    const int j_beg = s * (SP_N / 2);

    const unsigned short* qb = qt + ((size_t)b * SP_N + qtile * 64 + w * 16) * C_N;
    const unsigned short* kb = kt + (size_t)b * SP_N * C_N;
    const unsigned short* vb = vm + (size_t)b * SP_N * C_N;   // blocked

    bf16x8 qf[16];
#pragma unroll
    for (int ks = 0; ks < 16; ks++)
        qf[ks] = *(const bf16x8*)(qb + (size_t)lr * C_N + ks * 32 + g * 8);

    const f32x4 fz = {0.f, 0.f, 0.f, 0.f};
    f32x4 oacc[32];
#pragma unroll
    for (int i = 0; i < 32; i++) oacc[i] = fz;
    f32x4 mst = {-1e30f, -1e30f, -1e30f, -1e30f};
    f32x4 lst = {0.f, 0.f, 0.f, 0.f};

    for (int j0 = j_beg; j0 < j_beg + SP_N / 2; j0 += 32) {
        __syncthreads();   // all waves done reading LDS from previous iter

        // --- K tile [32][512] via global_load_lds DMA, pre-swizzled source ---
        // dest chunk p of row holds global chunk p^(row&7); lane l -> dest chunk l
#pragma unroll
        for (int r = 0; r < 8; r++) {
            int row = w * 8 + r;
            const unsigned short* src = kb + (size_t)(j0 + row) * C_N + (l ^ (row & 7)) * 8;
            GLOAD16(src, (char*)k_lds + row * 1024);
        }
        // --- V tile: contiguous 32KB chunk (blocked layout), reg-staged ---
        const unsigned short* vt = vb + (size_t)(j0 >> 5) * (C_N * 32);
        uint4 vdat[8];
#pragma unroll
        for (int r = 0; r < 8; r++) {
            int chunk = r * 256 + t;
            vdat[r] = *(const uint4*)(vt + (size_t)chunk * 8);
        }
#pragma unroll
        for (int r = 0; r < 8; r++) {
            int chunk = r * 256 + t;
            int c = chunk >> 2, jc = chunk & 3;
            *(uint4*)((char*)v_lds + c * 80 + jc * 16) = vdat[r];
        }
        __syncthreads();   // drains vmcnt(0): DMA K + V writes complete

        // S = Q K^T  (exp2 domain, scale folded into q)
        f32x4 s0 = fz, s1 = fz;
#pragma unroll
        for (int ks = 0; ks < 16; ks++) {
            bf16x8 kf0 = *(const bf16x8*)((const char*)k_lds + lr * 1024 + (((ks * 4 + g) ^ (lr & 7)) * 16));
            s0 = MFMA16(qf[ks], kf0, s0);
            int row1 = 16 + lr;
            bf16x8 kf1 = *(const bf16x8*)((const char*)k_lds + row1 * 1024 + (((ks * 4 + g) ^ (row1 & 7)) * 16));
            s1 = MFMA16(qf[ks], kf1, s1);
        }
        // row max over j (cols = lr within 16-lane group)
        f32x4 mt;
#pragma unroll
        for (int r = 0; r < 4; r++) mt[r] = fmaxf(s0[r], s1[r]);
#pragma unroll
        for (int msk = 1; msk <= 8; msk <<= 1) {
#pragma unroll
            for (int r = 0; r < 4; r++) mt[r] = fmaxf(mt[r], __shfl_xor(mt[r], msk));
        }
        int inc = (mt[0] > mst[0]) || (mt[1] > mst[1]) || (mt[2] > mst[2]) || (mt[3] > mst[3]);
        if (__any(inc)) {   // rescale only when running max grows (else P<=1 with old max)
            f32x4 alpha;
#pragma unroll
            for (int r = 0; r < 4; r++) {
                float mn = fmaxf(mst[r], mt[r]);
                alpha[r] = exp2f(mst[r] - mn);
                mst[r] = mn;
                lst[r] *= alpha[r];
            }
            int src = (lr >> 2) << 4;
            float a0 = __shfl(alpha[0], src), a1 = __shfl(alpha[1], src);
            float a2 = __shfl(alpha[2], src), a3 = __shfl(alpha[3], src);
            int rr = lr & 3;
            float ac = rr == 0 ? a0 : rr == 1 ? a1 : rr == 2 ? a2 : a3;
#pragma unroll
            for (int i = 0; i < 32; i++) {
#pragma unroll
                for (int r = 0; r < 4; r++) oacc[i][r] *= ac;
            }
        }
        f32x4 p0, p1, rsum;
#pragma unroll
        for (int r = 0; r < 4; r++) {
            p0[r] = exp2f(s0[r] - mst[r]);
            p1[r] = exp2f(s1[r] - mst[r]);
            rsum[r] = p0[r] + p1[r];
        }
#pragma unroll
        for (int msk = 1; msk <= 8; msk <<= 1) {
#pragma unroll
            for (int r = 0; r < 4; r++) rsum[r] += __shfl_xor(rsum[r], msk);
        }
#pragma unroll
        for (int r = 0; r < 4; r++) lst[r] += rsum[r];

        // P -> LDS (wave-private, 64B rows, chunk XOR (i>>1)&3), then O^T += V P^T
#pragma unroll
        for (int r = 0; r < 4; r++) {
            int i = g * 4 + r;
            int ja = lr;
            *(unsigned short*)((char*)p_lds[w] + i * 64 + (((ja >> 3) ^ ((i >> 1) & 3)) * 16) + (ja & 7) * 2) = f2bf(p0[r]);
            int jb = 16 + lr;
            *(unsigned short*)((char*)p_lds[w] + i * 64 + (((jb >> 3) ^ ((i >> 1) & 3)) * 16) + (jb & 7) * 2) = f2bf(p1[r]);
        }
        bf16x8 pf = *(const bf16x8*)((const char*)p_lds[w] + lr * 64 + ((g ^ ((lr >> 1) & 3)) * 16));
#pragma unroll
        for (int ct = 0; ct < 32; ct++) {
            int row = ct * 16 + lr;
            bf16x8 vf = *(const bf16x8*)((const char*)v_lds + row * 80 + g * 16);
            oacc[ct] = MFMA16(vf, pf, oacc[ct]);
        }
    }

    // epilogue: write UNNORMALIZED O_s [b][i][c] bf16 + per-row m,l
    unsigned short* aob = outp + ((size_t)b * SP_N + qtile * 64 + w * 16 + lr) * C_N;
#pragma unroll
    for (int ct = 0; ct < 32; ct++) {
        int c0 = ct * 16 + g * 4;
        ushort4 o4;
        o4.x = f2bf(oacc[ct][0]);
        o4.y = f2bf(oacc[ct][1]);
        o4.z = f2bf(oacc[ct][2]);
        o4.w = f2bf(oacc[ct][3]);
        *(ushort4*)(aob + c0) = o4;
    }
    if (lr == 0) {
        int base = (s * B_N + b) * SP_N + qtile * 64 + w * 16 + g * 4;
#pragma unroll
        for (int r = 0; r < 4; r++) {
            marr[base + r] = mst[r];
            larr[base + r] = lst[r];
        }
    }
}

// ---------------- combine 2 KV-splits ----------------
__global__ __launch_bounds__(256) void attn_combine(
        const unsigned short* __restrict__ o0,
        const unsigned short* __restrict__ o1,
        const float* __restrict__ marr,
        const float* __restrict__ larr,
        unsigned short* __restrict__ ao) {
    const int w = threadIdx.x >> 6, l = threadIdx.x & 63;
    const size_t row = (size_t)blockIdx.x * 4 + w;   // b*N + n, 0..16383
    float m0 = marr[row], m1 = marr[B_N * SP_N + row];
    float l0 = larr[row], l1 = larr[B_N * SP_N + row];
    float m = fmaxf(m0, m1);
    float w0 = exp2f(m0 - m), w1 = exp2f(m1 - m);
    float den = w0 * l0 + w1 * l1;
    float a0 = w0 / den, a1 = w1 / den;
    uint4 u0 = *(const uint4*)(o0 + row * C_N + l * 8);
    uint4 u1 = *(const uint4*)(o1 + row * C_N + l * 8);
    const unsigned short* s0p = (const unsigned short*)&u0;
    const unsigned short* s1p = (const unsigned short*)&u1;
    unsigned short r8[8];
#pragma unroll
    for (int i = 0; i < 8; i++)
        r8[i] = f2bf(a0 * bf2f(s0p[i]) + a1 * bf2f(s1p[i]));
    *(uint4*)(ao + row * C_N + l * 8) = *(const uint4*)r8;
}

extern "C" void kernel_launch(void* const* d_in, const int* in_sizes, int n_in,
                              void* d_out, int out_size, void* d_ws, size_t ws_size,
                              hipStream_t stream) {
    const float* x   = (const float*)d_in[0];
    const float* gam = (const float*)d_in[1];
    const float* bet = (const float*)d_in[2];
    const float* wq  = (const float*)d_in[3];
    const float* bq  = (const float*)d_in[4];
    const float* wk  = (const float*)d_in[5];
    const float* bk  = (const float*)d_in[6];
    const float* wv  = (const float*)d_in[7];
    const float* bv  = (const float*)d_in[8];
    const float* wp  = (const float*)d_in[9];
    const float* bp  = (const float*)d_in[10];

    char* ws = (char*)d_ws;
    const size_t SZ = (size_t)B_N * SP_N * C_N * 2;   // 16 MiB per bf16 tensor
    unsigned short* h_t = (unsigned short*)(ws);
    unsigned short* q_t = (unsigned short*)(ws + SZ);
    unsigned short* k_t = (unsigned short*)(ws + 2 * SZ);
    unsigned short* v_m = (unsigned short*)(ws + 3 * SZ);
    unsigned short* wbf = (unsigned short*)(ws + 4 * SZ);
    unsigned short* wq_b = wbf;
    unsigned short* wk_b = wbf + 262144;
    unsigned short* wv_b = wbf + 2 * 262144;
    unsigned short* wp_b = wbf + 3 * 262144;
    float* marr = (float*)(ws + 4 * SZ + 4 * 524288);          // [2][B][N]
    float* larr = marr + 2 * B_N * SP_N;

    unsigned short* o0 = h_t;                       // h_t dead after V gemm
    unsigned short* o1 = (unsigned short*)d_out;    // d_out (33.5MB) spare as scratch
    unsigned short* ao = q_t;                       // q_t dead after attn

    const float qs = 0.044194173824159216f * 1.4426950408889634f;  // C^-0.5 * log2(e)

    wconv<<<dim3(256, 4), 256, 0, stream>>>(wq, wk, wv, wp, wbf);
    gn_kernel<<<dim3(128), 512, 0, stream>>>(x, gam, bet, h_t);
    gemm_nt<0><<<dim3(32, 4, 4), 256, 0, stream>>>(h_t, wq_b, q_t, bq, nullptr, qs);
    gemm_nt<1><<<dim3(32, 4, 4), 256, 0, stream>>>(h_t, wk_b, k_t, bk, nullptr, 1.f);
    gemm_nt<2><<<dim3(4, 32, 4), 256, 0, stream>>>(wv_b, h_t, v_m, bv, nullptr, 1.f);
    attn_kernel<<<dim3(512), 256, 0, stream>>>(q_t, k_t, v_m, o0, o1, marr, larr);
    attn_combine<<<dim3(B_N * SP_N / 4), 256, 0, stream>>>(o0, o1, marr, larr, ao);
    gemm_nt<3><<<dim3(4, 32, 4), 256, 0, stream>>>(wp_b, ao, d_out, bp, x, 1.f);
}